// Round 1
// baseline (135.628 us; speedup 1.0000x reference)
//
#include <hip/hip_runtime.h>

// OESNN_SEPhIA_MultiTiled2: 32-step recurrent SNN, B=8192.
// R3: occupancy fix. rocprof showed 1 wave/SIMD (Occupancy 8.2%), VALUBusy
// 16.6%, HBM 21% -> latency-bound, no pipe saturated. Go 8 -> 32 lanes per
// batch element: 4096 waves = 4 waves/SIMD. Each lane owns EITHER one layer-0
// channel (lanes 0..17) OR one layer-1 output (lanes 18..25), both stored in
// the SAME wA/wB register arrays (36 regs) so per-lane VGPR stays ~<100 and
// __launch_bounds__(256,4) holds 4 waves/SIMD resident.
// Numerics are op-for-op identical to the R2 passing kernel: p = x*1e-4
// (single rounding) feeding ascending-w single-accumulator fma chains,
// select-based LIF, pw gathered by __shfl (pure selection).

namespace {
constexpr int Tn = 32;
constexpr int Bn = 8192;
constexpr int O_PW = 0;                       // spks0 (= pw0) [T,B,18]
constexpr int O_S1 = Tn * Bn * 18;            // spks1 [T,B,8]
constexpr int O_M0 = O_S1 + Tn * Bn * 8;      // mems0 [T,B,18]
constexpr int O_M1 = O_M0 + Tn * Bn * 18;     // mems1 [T,B,8]
}

__global__ __launch_bounds__(256, 4)
void oesnn_kernel(const float* __restrict__ x_in,
                  const float* __restrict__ W0g,   // [2,18,18]
                  const float* __restrict__ d0g,   // [2,9]
                  const float* __restrict__ W1g,   // [1,18,16]
                  const float* __restrict__ d1g,   // [1,8]
                  const float* __restrict__ peakg, // [36]
                  float* __restrict__ out)
{
    const int lt  = threadIdx.x & 63;         // lane in wave
    const int tid = blockIdx.x * 256 + threadIdx.x;
    const int b   = tid >> 5;                 // batch element (32 lanes/elem)
    const int g   = tid & 31;                 // lane within batch group
    const bool isL0 = (g < 18);
    const bool isL1 = (g >= 18) && (g < 26);

    // ---------------- per-lane weight preload into registers ----------------
    // Layer-0 lane g<18: channel c=g (tile tl=c/9, in-tile jc=c%9), even/odd
    // W0 columns. Layer-1 lane 18<=g<26: output o=g-18, even/odd W1 columns.
    // Shared arrays keep the union footprint at 36 regs, not 72.
    float wA[18], wB[18];
    float dd = 0.f, pon = 0.f, poff = 0.f;
    int tl = 0;

    if (isL0) {
        tl = g / 9;
        const int jc = g % 9;
        dd = d0g[tl * 9 + jc];
        #pragma unroll
        for (int w = 0; w < 18; ++w) {
            const float2 p = *(const float2*)(W0g + ((tl * 18 + w) * 18 + 2 * jc));
            wA[w] = p.x;
            wB[w] = p.y;
        }
        // pw0 takes exactly two values per channel: precompute via the
        // reference's complex-division -> abs -> square path (verbatim R2).
        const int c = g;
        const float wl    = 1550.0f + 0.8f * (float)c;
        const float halfw = 0.5f * (wl * 1e3f / 15000.0f);
        const float amp   = sqrtf((exp10f(peakg[c] / 10.0f) / 1000.0f) * 1e6f);
        {   // spike = 0: lo = (0.1 + 0i)/(1 + 0i) * amp
            const float lr = 0.1f * amp;
            const float a  = sqrtf(lr * lr);
            poff = a * a;
        }
        {   // spike = 1: delta = -250 / (0.5*fwhm)
            const float delta = -250.0f / halfw;
            const float den = fmaf(delta, delta, 1.0f);
            const float qr  = fmaf(delta, delta, 0.1f) / den;     // (g + d^2)/den
            const float qi  = (delta - 0.1f * delta) / den;       // (d - g*d)/den
            const float lr = qr * amp, li = qi * amp;
            const float a  = sqrtf(fmaf(lr, lr, li * li));
            pon = a * a;
        }
    } else {
        const int o = (g < 26) ? (g - 18) : 7;   // clamp idle lanes 26..31
        dd = d1g[o];
        #pragma unroll
        for (int w = 0; w < 18; ++w) {
            const float2 p = *(const float2*)(W1g + w * 16 + 2 * o);  // 8B-aligned
            wA[w] = p.x;
            wB[w] = p.y;
        }
    }

    // ---------------- state & pointers ----------------
    float mem0 = 0.f;   // layer-0 lanes: their channel's membrane
    float mem1 = 0.f;   // layer-1 lanes: their output's membrane

    const float* xp = x_in + (size_t)b * 36 + tl * 18;   // tl=0 for non-L0 lanes
    float* opw = out + O_PW + (size_t)b * 18 + g;        // valid when isL0
    float* om0 = out + O_M0 + (size_t)b * 18 + g;
    const int o1 = isL1 ? (g - 18) : 0;
    float* os1 = out + O_S1 + (size_t)b * 8 + o1;        // valid when isL1
    float* om1 = out + O_M1 + (size_t)b * 8 + o1;

    // prefetch t=0 inputs (18 floats = 9x float2, 8B-aligned)
    float2 xv[9];
    #pragma unroll
    for (int k = 0; k < 9; ++k) xv[k] = *(const float2*)(xp + 2 * k);

    const int basel = lt & ~31;   // first lane of this 32-lane batch group

    #pragma unroll 1
    for (int t = 0; t < Tn; ++t) {
        // ---- layer 0: even/odd column dot (ascending w, single accumulator,
        // p = x*1e-4 rounded once -- identical arithmetic to R2) ----
        float se = 0.f, so = 0.f;
        #pragma unroll
        for (int k = 0; k < 9; ++k) {
            const float pa = xv[k].x * 1e-4f;
            se = fmaf(pa, wA[2 * k], se);
            so = fmaf(pa, wB[2 * k], so);
            const float pb = xv[k].y * 1e-4f;
            se = fmaf(pb, wA[2 * k + 1], se);
            so = fmaf(pb, wB[2 * k + 1], so);
        }

        // prefetch next timestep while the rest of this one computes
        xp += Bn * 36;
        if (t < Tn - 1) {
            #pragma unroll
            for (int k = 0; k < 9; ++k) xv[k] = *(const float2*)(xp + 2 * k);
        }

        // ---- layer-0 LIF + MRR power (garbage on non-L0 lanes, never read) --
        const float c0 = (se - so) * dd;
        const float m2 = (mem0 > 0.55f) ? 0.0f : fmaf(0.95f, mem0, c0);
        mem0 = m2;
        const float pw = (m2 > 0.55f) ? pon : poff;

        if (isL0) {
            *opw = pw;    // lanes 0..17 + 32..49: 36 consecutive dwords/wave
            *om0 = m2;
        }

        // ---- layer 1: gather 18 pw values from layer-0 lanes, ascending-c
        // fma chain (identical order to R2's pwall loop) ----
        float i1e = 0.f, i1o = 0.f;
        #pragma unroll
        for (int c = 0; c < 18; ++c) {
            const float gp = __shfl(pw, basel + c, 64);
            i1e = fmaf(gp, wA[c], i1e);
            i1o = fmaf(gp, wB[c], i1o);
        }

        const float c1 = (i1e - i1o) * dd;
        const float m3 = (mem1 > 0.25f) ? 0.0f : fmaf(0.95f, mem1, c1);
        mem1 = m3;
        if (isL1) {
            *os1 = (m3 > 0.25f) ? 1.0f : 0.0f;  // lanes 18..25 + 50..57: 16 dwords
            *om1 = m3;
        }

        opw += Bn * 18;
        om0 += Bn * 18;
        os1 += Bn * 8;
        om1 += Bn * 8;
    }
}

extern "C" void kernel_launch(void* const* d_in, const int* in_sizes, int n_in,
                              void* d_out, int out_size, void* d_ws, size_t ws_size,
                              hipStream_t stream) {
    (void)in_sizes; (void)n_in; (void)out_size; (void)d_ws; (void)ws_size;
    const float* x  = (const float*)d_in[0];
    const float* W0 = (const float*)d_in[1];
    const float* d0 = (const float*)d_in[2];
    const float* W1 = (const float*)d_in[3];
    const float* d1 = (const float*)d_in[4];
    const float* pk = (const float*)d_in[5];
    float* out = (float*)d_out;

    dim3 grid(Bn * 32 / 256), block(256);   // 262144 threads = 4096 waves
    hipLaunchKernelGGL(oesnn_kernel, grid, block, 0, stream,
                       x, W0, d0, W1, d1, pk, out);
}